// Round 11
// baseline (178.896 us; speedup 1.0000x reference)
//
#include <hip/hip_runtime.h>
#include <cstdint>
#include <cstddef>

// GlobalAttention (Luong 'general'): q = src@W^T ; x = q@MB^T ; softmax(mask) ; c = P@MB
// Outputs: d_out = [ c (8*1024*256) | align_vectors (8*1024*4096) ] fp32.
// Pipeline: k_qproj -> k_logits6 (s-chunk-resident, barrier-free QK + x-store +
//   exact chunk stats) -> k_stats (32 chunks) -> k_pv (x->p + PV) -> k_csum
//
// R11: logits5 (86us) moved 390 MB at 4.5 TB/s: staging re-read mbank 8x (once
// per t-tile) and per-step barriers forced store drains. logits6 inverts the
// loop: each block owns a 128-s chunk (staged ONCE -> 32 MB total, 8x cut),
// loops over all 1024 t re-reading only the L2-resident 512KB q16 slab, and is
// BARRIER-FREE after the single staging sync (Bs read-only). Stats per chunk
// are exact single-pass (no online merge). qproj/pv/csum frozen from R10.

typedef _Float16 f16;
typedef _Float16 half8 __attribute__((ext_vector_type(8)));
typedef _Float16 half4v __attribute__((ext_vector_type(4)));
typedef float f32x4 __attribute__((ext_vector_type(4)));

#define MFMA16(a, b, c) __builtin_amdgcn_mfma_f32_16x16x32_f16((a), (b), (c), 0, 0, 0)

static constexpr int NBATCH = 8;
static constexpr int NT = 1024;   // TGT
static constexpr int NS = 4096;   // SRC
static constexpr int ND = 256;    // SDIM == TDIM
static constexpr float NEGBIG = -3.0e38f;

__device__ __forceinline__ int swz(int row, int byteInRow) {
  return byteInRow ^ ((row & 7) << 4);
}

// ---------------- K1: q16 = source @ W^T (fp16 out) ----------------
__global__ __launch_bounds__(256) void k_qproj(const float* __restrict__ src,
                                               const float* __restrict__ W,
                                               f16* __restrict__ q16) {
  __shared__ __align__(16) f16 As[64 * 64];
  __shared__ __align__(16) f16 Bs[256 * 64];
  const int tid = threadIdx.x;
  const int w = tid >> 6, l = tid & 63;
  const int wt = w >> 1, wn = w & 1;
  const int q = l >> 4, lc = l & 15;
  const int t0 = blockIdx.x * 64;

  f32x4 acc[2][8];
#pragma unroll
  for (int i = 0; i < 2; ++i)
#pragma unroll
    for (int j = 0; j < 8; ++j) acc[i][j] = (f32x4){0.f, 0.f, 0.f, 0.f};

  for (int k0 = 0; k0 < 256; k0 += 64) {
    __syncthreads();
    {
      const int r = tid >> 2, c2 = (tid & 3) * 2;
      const float* g = src + (size_t)(t0 + r) * 256 + k0 + c2 * 8;
      float4 f0 = ((const float4*)g)[0], f1 = ((const float4*)g)[1];
      float4 f2 = ((const float4*)g)[2], f3 = ((const float4*)g)[3];
      half8 h0 = {(f16)f0.x, (f16)f0.y, (f16)f0.z, (f16)f0.w,
                  (f16)f1.x, (f16)f1.y, (f16)f1.z, (f16)f1.w};
      half8 h1 = {(f16)f2.x, (f16)f2.y, (f16)f2.z, (f16)f2.w,
                  (f16)f3.x, (f16)f3.y, (f16)f3.z, (f16)f3.w};
      *(half8*)((char*)As + r * 128 + swz(r, c2 * 16)) = h0;
      *(half8*)((char*)As + r * 128 + swz(r, c2 * 16 + 16)) = h1;
    }
    {
      const int n = tid;
      const float* g = W + (size_t)n * 256 + k0;
#pragma unroll
      for (int c = 0; c < 8; ++c) {
        float4 f0 = ((const float4*)(g + c * 8))[0];
        float4 f1 = ((const float4*)(g + c * 8))[1];
        half8 h = {(f16)f0.x, (f16)f0.y, (f16)f0.z, (f16)f0.w,
                   (f16)f1.x, (f16)f1.y, (f16)f1.z, (f16)f1.w};
        *(half8*)((char*)Bs + n * 128 + swz(n, c * 16)) = h;
      }
    }
    __syncthreads();
    half8 a[2][2], bb[8][2];
#pragma unroll
    for (int mb = 0; mb < 2; ++mb)
#pragma unroll
      for (int kf = 0; kf < 2; ++kf) {
        const int r = wt * 32 + mb * 16 + lc;
        a[mb][kf] = *(const half8*)((const char*)As + r * 128 + swz(r, kf * 64 + q * 16));
      }
#pragma unroll
    for (int nb = 0; nb < 8; ++nb)
#pragma unroll
      for (int kf = 0; kf < 2; ++kf) {
        const int r = wn * 128 + nb * 16 + lc;
        bb[nb][kf] = *(const half8*)((const char*)Bs + r * 128 + swz(r, kf * 64 + q * 16));
      }
#pragma unroll
    for (int kf = 0; kf < 2; ++kf)
#pragma unroll
      for (int mb = 0; mb < 2; ++mb)
#pragma unroll
        for (int nb = 0; nb < 8; ++nb)
          acc[mb][nb] = MFMA16(a[mb][kf], bb[nb][kf], acc[mb][nb]);
  }
#pragma unroll
  for (int mb = 0; mb < 2; ++mb)
#pragma unroll
    for (int nb = 0; nb < 8; ++nb)
#pragma unroll
      for (int j = 0; j < 4; ++j) {
        const int t = t0 + wt * 32 + mb * 16 + q * 4 + j;
        const int n = wn * 128 + nb * 16 + lc;
        q16[(size_t)t * 256 + n] = (f16)acc[mb][nb][j];
      }
}

// ---------------- K2: s-chunk-resident QK + x-store + exact chunk stats --------
// grid 256: b = bid&7 (XCD pin), kc = bid>>3 (0..31, 128-s chunk). block 512 =
// 8 waves x 32 t-rows per tt; tt loops 4 x 256 t. Bs staged ONCE; barrier-free
// after. Swapped-operand MFMA: lane holds x[s=q*4+j][t=lc], float4 stores.
__global__ __launch_bounds__(512, 2) void k_logits6(const float* __restrict__ mbank,
                                                    const f16* __restrict__ q16,
                                                    const int* __restrict__ mask,
                                                    float* __restrict__ alignv,
                                                    float* __restrict__ pstats) {
  __shared__ __align__(16) f16 Bs[128 * 256];  // [s][d] f16, 512B rows, swz (64 KB)
  const int tid = threadIdx.x;
  const int w = tid >> 6, l = tid & 63;
  const int q = l >> 4, lc = l & 15;
  const int bid = blockIdx.x;
  const int b = bid & 7;
  const int kc = bid >> 3;
  const int s0 = kc * 128;

  {  // stage Bs[128][256] fp32 -> f16, once
    const int r = tid >> 2;
    const int c0 = (tid & 3) * 64;
    const float4* g = (const float4*)(mbank + ((size_t)b * NS + s0 + r) * ND + c0);
#pragma unroll
    for (int i = 0; i < 8; ++i) {
      float4 f0 = g[2 * i], f1 = g[2 * i + 1];
      half8 h = {(f16)f0.x, (f16)f0.y, (f16)f0.z, (f16)f0.w,
                 (f16)f1.x, (f16)f1.y, (f16)f1.z, (f16)f1.w};
      *(half8*)((char*)Bs + r * 512 + swz(r, c0 * 2 + i * 16)) = h;
    }
  }
  // hoist masks for this lane's s-positions (s = nb*16 + q*4 + j)
  int4 mk[8];
#pragma unroll
  for (int nb = 0; nb < 8; ++nb)
    mk[nb] = *(const int4*)(mask + (size_t)b * NS + s0 + nb * 16 + q * 4);
  __syncthreads();  // Bs read-only from here: NO further barriers

  for (int tt = 0; tt < 4; ++tt) {
    const int t0 = tt * 256 + w * 32;  // this wave's 32-t group
    // q fragments (B-operand role) for 2 x 16 t-rows
    half8 aq[2][8];
#pragma unroll
    for (int mb = 0; mb < 2; ++mb) {
      const f16* qrow = q16 + (size_t)(b * NT + t0 + mb * 16 + lc) * 256;
#pragma unroll
      for (int kf = 0; kf < 8; ++kf)
        aq[mb][kf] = *(const half8*)(qrow + kf * 32 + q * 8);
    }
    // xT[mb][nb] over full 128-s chunk; B-frag (mbf) shared across mb
    f32x4 xT[2][8];
#pragma unroll
    for (int mb = 0; mb < 2; ++mb)
#pragma unroll
      for (int nb = 0; nb < 8; ++nb) xT[mb][nb] = (f32x4){0.f, 0.f, 0.f, 0.f};
#pragma unroll
    for (int kf = 0; kf < 8; ++kf)
#pragma unroll
      for (int nb = 0; nb < 8; ++nb) {
        const int rs = nb * 16 + lc;
        half8 mbf = *(const half8*)((const char*)Bs + rs * 512 + swz(rs, kf * 64 + q * 16));
        xT[0][nb] = MFMA16(mbf, aq[0][kf], xT[0][nb]);
        xT[1][nb] = MFMA16(mbf, aq[1][kf], xT[1][nb]);
      }
    // per mb: mask -> store -> exact stats over the 128-s chunk
#pragma unroll
    for (int mb = 0; mb < 2; ++mb) {
      const int t = t0 + mb * 16 + lc;
      float* ab = alignv + ((size_t)b * NT + t) * NS + s0;
      float vmax = NEGBIG;
      float v[8][4];
#pragma unroll
      for (int nb = 0; nb < 8; ++nb) {
        v[nb][0] = mk[nb].x ? xT[mb][nb][0] : NEGBIG;
        v[nb][1] = mk[nb].y ? xT[mb][nb][1] : NEGBIG;
        v[nb][2] = mk[nb].z ? xT[mb][nb][2] : NEGBIG;
        v[nb][3] = mk[nb].w ? xT[mb][nb][3] : NEGBIG;
        *(float4*)(ab + nb * 16 + q * 4) = (float4){v[nb][0], v[nb][1], v[nb][2], v[nb][3]};
        vmax = fmaxf(vmax, fmaxf(fmaxf(v[nb][0], v[nb][1]), fmaxf(v[nb][2], v[nb][3])));
      }
      vmax = fmaxf(vmax, __shfl_xor(vmax, 16));
      vmax = fmaxf(vmax, __shfl_xor(vmax, 32));
      float vsum = 0.f;
#pragma unroll
      for (int nb = 0; nb < 8; ++nb)
#pragma unroll
        for (int j = 0; j < 4; ++j) vsum += __expf(v[nb][j] - vmax);
      vsum += __shfl_xor(vsum, 16);
      vsum += __shfl_xor(vsum, 32);
      if (l < 16) {
        pstats[(((size_t)b * NT + t) * 32 + kc) * 2 + 0] = vmax;
        pstats[(((size_t)b * NT + t) * 32 + kc) * 2 + 1] = vsum;
      }
    }
  }
}

// ---------------- K3: reduce 32 chunk partials -> m, 1/l per row ----------------
__global__ __launch_bounds__(256) void k_stats(const float* __restrict__ pstats,
                                               float* __restrict__ sm,
                                               float* __restrict__ slinv) {
  const int r = blockIdx.x * 256 + threadIdx.x;
  const float4* p = (const float4*)(pstats + (size_t)r * 64);
  float4 v[16];
  float mm = NEGBIG;
#pragma unroll
  for (int i = 0; i < 16; ++i) {
    v[i] = p[i];
    mm = fmaxf(mm, fmaxf(v[i].x, v[i].z));
  }
  float ll = 0.f;
#pragma unroll
  for (int i = 0; i < 16; ++i)
    ll += v[i].y * __expf(v[i].x - mm) + v[i].w * __expf(v[i].z - mm);
  sm[r] = mm;
  slinv[r] = (ll > 0.f) ? (1.f / ll) : 0.f;
}

// ---------------- K4: p = exp(x-m)/l (once per element, in place) ; partial c = P@V ----
// R4's measured-fast kernel; flat grid 512 with b = bid&7 XCD pin. (frozen)
__global__ __launch_bounds__(512, 4) void k_pv(const float* __restrict__ mbank,
                                               const float* __restrict__ sm,
                                               const float* __restrict__ slinv,
                                               float* __restrict__ alignv,
                                               f16* __restrict__ pc) {
  __shared__ __align__(16) f16 VT[256 * 64];
  __shared__ __align__(16) f16 Ps[64 * 64];
  const int tid = threadIdx.x;
  const int w = tid >> 6, l = tid & 63;
  const int wtg = w >> 2, wd = w & 3;
  const int q = l >> 4, lc = l & 15;
  const int bid = blockIdx.x;
  const int b = bid & 7;
  const int kc = (bid >> 3) & 3;
  const int tt = bid >> 5;
  const int t0 = tt * 64;
  const int s0 = kc * 1024;

  const int pt = tid >> 3;
  const int ps8 = (tid & 7) * 8;
  const float mv = sm[(size_t)b * NT + t0 + pt];
  const float lv = slinv[(size_t)b * NT + t0 + pt];
  float* xrow = alignv + ((size_t)b * NT + t0 + pt) * NS + s0 + ps8;

  f32x4 acc[2][4];
#pragma unroll
  for (int i = 0; i < 2; ++i)
#pragma unroll
    for (int j = 0; j < 4; ++j) acc[i][j] = (f32x4){0.f, 0.f, 0.f, 0.f};

  const int dstage = (w & 3) * 64 + l;
  const int shalf = (w >> 2) * 32;

  float4 xA = ((const float4*)xrow)[0];
  float4 xB = ((const float4*)xrow)[1];

  for (int st = 0; st < 16; ++st) {
    const int sb = s0 + st * 64;
    __syncthreads();
    {
#pragma unroll
      for (int i = 0; i < 8; ++i) {
        const int s4 = shalf + i * 4;
        const float* g = mbank + ((size_t)b * NS + sb + s4) * ND + dstage;
        const float f0 = g[0], f1 = g[ND], f2 = g[2 * ND], f3 = g[3 * ND];
        half4v h = {(f16)f0, (f16)f1, (f16)f2, (f16)f3};
        *(half4v*)((char*)VT + dstage * 128 + swz(dstage, s4 * 2)) = h;
      }
    }
    {
      const float p0 = __expf(xA.x - mv) * lv, p1 = __expf(xA.y - mv) * lv;
      const float p2 = __expf(xA.z - mv) * lv, p3 = __expf(xA.w - mv) * lv;
      const float p4 = __expf(xB.x - mv) * lv, p5 = __expf(xB.y - mv) * lv;
      const float p6 = __expf(xB.z - mv) * lv, p7 = __expf(xB.w - mv) * lv;
      float* xp = xrow + st * 64;
      ((float4*)xp)[0] = (float4){p0, p1, p2, p3};
      ((float4*)xp)[1] = (float4){p4, p5, p6, p7};
      half8 h = {(f16)p0, (f16)p1, (f16)p2, (f16)p3,
                 (f16)p4, (f16)p5, (f16)p6, (f16)p7};
      *(half8*)((char*)Ps + pt * 128 + swz(pt, ps8 * 2)) = h;
    }
    if (st < 15) {
      const float* xn = xrow + (st + 1) * 64;
      xA = ((const float4*)xn)[0];
      xB = ((const float4*)xn)[1];
    }
    __syncthreads();
    half8 a[2][2];
#pragma unroll
    for (int mb = 0; mb < 2; ++mb)
#pragma unroll
      for (int kf = 0; kf < 2; ++kf) {
        const int r = wtg * 32 + mb * 16 + lc;
        a[mb][kf] = *(const half8*)((const char*)Ps + r * 128 + swz(r, kf * 64 + q * 16));
      }
#pragma unroll
    for (int kf = 0; kf < 2; ++kf)
#pragma unroll
      for (int nb = 0; nb < 4; ++nb) {
        const int d = wd * 64 + nb * 16 + lc;
        half8 bbt = *(const half8*)((const char*)VT + d * 128 + swz(d, kf * 64 + q * 16));
#pragma unroll
        for (int mb = 0; mb < 2; ++mb)
          acc[mb][nb] = MFMA16(a[mb][kf], bbt, acc[mb][nb]);
      }
  }

#pragma unroll
  for (int mb = 0; mb < 2; ++mb)
#pragma unroll
    for (int nb = 0; nb < 4; ++nb)
#pragma unroll
      for (int j = 0; j < 4; ++j) {
        const int t = t0 + wtg * 32 + mb * 16 + q * 4 + j;
        const int d = wd * 64 + nb * 16 + lc;
        pc[(size_t)kc * ((size_t)NBATCH * NT * ND) + ((size_t)b * NT + t) * ND + d] =
            (f16)acc[mb][nb][j];
      }
}

// ---------------- K5: c = sum of 4 fp16 split-K partials ----------------
__global__ __launch_bounds__(256) void k_csum(const f16* __restrict__ pc,
                                              float* __restrict__ outc) {
  const size_t i8 = ((size_t)blockIdx.x * 256 + threadIdx.x) * 8;
  const size_t STRIDE = (size_t)NBATCH * NT * ND;
  half8 a = *(const half8*)(pc + i8);
  half8 b = *(const half8*)(pc + STRIDE + i8);
  half8 c = *(const half8*)(pc + 2 * STRIDE + i8);
  half8 d = *(const half8*)(pc + 3 * STRIDE + i8);
  float4 r0, r1;
  r0.x = (float)a[0] + (float)b[0] + (float)c[0] + (float)d[0];
  r0.y = (float)a[1] + (float)b[1] + (float)c[1] + (float)d[1];
  r0.z = (float)a[2] + (float)b[2] + (float)c[2] + (float)d[2];
  r0.w = (float)a[3] + (float)b[3] + (float)c[3] + (float)d[3];
  r1.x = (float)a[4] + (float)b[4] + (float)c[4] + (float)d[4];
  r1.y = (float)a[5] + (float)b[5] + (float)c[5] + (float)d[5];
  r1.z = (float)a[6] + (float)b[6] + (float)c[6] + (float)d[6];
  r1.w = (float)a[7] + (float)b[7] + (float)c[7] + (float)d[7];
  *(float4*)(outc + i8) = r0;
  *(float4*)(outc + i8 + 4) = r1;
}

extern "C" void kernel_launch(void* const* d_in, const int* in_sizes, int n_in,
                              void* d_out, int out_size, void* d_ws, size_t ws_size,
                              hipStream_t stream) {
  const float* mbank = (const float*)d_in[0];  // (8,4096,256) f32
  const float* src   = (const float*)d_in[1];  // (8,1024,256) f32
  const int*   mask  = (const int*)d_in[2];    // (8,4096) bool->int
  const float* W     = (const float*)d_in[3];  // (256,256) f32

  float* out_c = (float*)d_out;
  float* out_align = out_c + (size_t)NBATCH * NT * ND;

  // ws layout (24 MB total):
  //   [0, 4 MB)          q16   : 8192x256 fp16
  //   [4 MB, 6 MB)       pstats: 8192x32x2 f32
  //   [6 MB, +32 KB)     sm
  //   [6 MB+32K, +32K)   slinv
  //   [8 MB, 24 MB)      pc    : 4 x 2M fp16 split-K partials
  char* ws = (char*)d_ws;
  f16* q16      = (f16*)ws;
  float* pstats = (float*)(ws + (4 << 20));
  float* sm     = (float*)(ws + (6 << 20));
  float* slinv  = (float*)(ws + (6 << 20) + (32 << 10));
  f16* pc       = (f16*)(ws + (8 << 20));

  hipLaunchKernelGGL(k_qproj, dim3(128), dim3(256), 0, stream, src, W, q16);
  hipLaunchKernelGGL(k_logits6, dim3(256), dim3(512), 0, stream,
                     mbank, q16, mask, out_align, pstats);
  hipLaunchKernelGGL(k_stats, dim3(32), dim3(256), 0, stream, pstats, sm, slinv);
  hipLaunchKernelGGL(k_pv, dim3(512), dim3(512), 0, stream,
                     mbank, sm, slinv, out_align, pc);
  hipLaunchKernelGGL(k_csum, dim3(1024), dim3(256), 0, stream, pc, out_c);
}

// Round 13
// 170.538 us; speedup vs baseline: 1.0490x; 1.0490x over previous
//
#include <hip/hip_runtime.h>
#include <cstdint>
#include <cstddef>

// GlobalAttention (Luong 'general'): q = src@W^T ; x = q@MB^T ; softmax(mask) ; c = P@MB
// Outputs: d_out = [ c (8*1024*256) | align_vectors (8*1024*4096) ] fp32.
// Pipeline: k_qproj -> k_logits7 (stage-once, barrier-free, nt x-store, exact
//   64-chunk stats) -> k_stats (64 chunks) -> k_pv (frozen) -> k_csum (frozen)
//
// R13 = R12 with the compile fix: __builtin_nontemporal_store requires a clang
// ext_vector type, not HIP's float4 class -> store f32x4 through an f32x4*.
// Design rationale (R12): R11's loop-inversion failed from (i) 1 block/CU and
// (ii) q16 re-reads evicted by the cached x-store stream (FETCH 146 MB).
// logits7: s-chunk 64 -> grid 512 (2 blocks/CU); x-stores NONTEMPORAL 16-B
// (64-B coalesced segments per 16-lane group) so the 512KB/batch q16 slab stays
// L2-resident; Bs staged once; ONE barrier; stores pipeline to kernel end.

typedef _Float16 f16;
typedef _Float16 half8 __attribute__((ext_vector_type(8)));
typedef _Float16 half4v __attribute__((ext_vector_type(4)));
typedef float f32x4 __attribute__((ext_vector_type(4)));

#define MFMA16(a, b, c) __builtin_amdgcn_mfma_f32_16x16x32_f16((a), (b), (c), 0, 0, 0)

static constexpr int NBATCH = 8;
static constexpr int NT = 1024;   // TGT
static constexpr int NS = 4096;   // SRC
static constexpr int ND = 256;    // SDIM == TDIM
static constexpr float NEGBIG = -3.0e38f;

__device__ __forceinline__ int swz(int row, int byteInRow) {
  return byteInRow ^ ((row & 7) << 4);
}

// ---------------- K1: q16 = source @ W^T (fp16 out) ---------------- (frozen)
__global__ __launch_bounds__(256) void k_qproj(const float* __restrict__ src,
                                               const float* __restrict__ W,
                                               f16* __restrict__ q16) {
  __shared__ __align__(16) f16 As[64 * 64];
  __shared__ __align__(16) f16 Bs[256 * 64];
  const int tid = threadIdx.x;
  const int w = tid >> 6, l = tid & 63;
  const int wt = w >> 1, wn = w & 1;
  const int q = l >> 4, lc = l & 15;
  const int t0 = blockIdx.x * 64;

  f32x4 acc[2][8];
#pragma unroll
  for (int i = 0; i < 2; ++i)
#pragma unroll
    for (int j = 0; j < 8; ++j) acc[i][j] = (f32x4){0.f, 0.f, 0.f, 0.f};

  for (int k0 = 0; k0 < 256; k0 += 64) {
    __syncthreads();
    {
      const int r = tid >> 2, c2 = (tid & 3) * 2;
      const float* g = src + (size_t)(t0 + r) * 256 + k0 + c2 * 8;
      float4 f0 = ((const float4*)g)[0], f1 = ((const float4*)g)[1];
      float4 f2 = ((const float4*)g)[2], f3 = ((const float4*)g)[3];
      half8 h0 = {(f16)f0.x, (f16)f0.y, (f16)f0.z, (f16)f0.w,
                  (f16)f1.x, (f16)f1.y, (f16)f1.z, (f16)f1.w};
      half8 h1 = {(f16)f2.x, (f16)f2.y, (f16)f2.z, (f16)f2.w,
                  (f16)f3.x, (f16)f3.y, (f16)f3.z, (f16)f3.w};
      *(half8*)((char*)As + r * 128 + swz(r, c2 * 16)) = h0;
      *(half8*)((char*)As + r * 128 + swz(r, c2 * 16 + 16)) = h1;
    }
    {
      const int n = tid;
      const float* g = W + (size_t)n * 256 + k0;
#pragma unroll
      for (int c = 0; c < 8; ++c) {
        float4 f0 = ((const float4*)(g + c * 8))[0];
        float4 f1 = ((const float4*)(g + c * 8))[1];
        half8 h = {(f16)f0.x, (f16)f0.y, (f16)f0.z, (f16)f0.w,
                   (f16)f1.x, (f16)f1.y, (f16)f1.z, (f16)f1.w};
        *(half8*)((char*)Bs + n * 128 + swz(n, c * 16)) = h;
      }
    }
    __syncthreads();
    half8 a[2][2], bb[8][2];
#pragma unroll
    for (int mb = 0; mb < 2; ++mb)
#pragma unroll
      for (int kf = 0; kf < 2; ++kf) {
        const int r = wt * 32 + mb * 16 + lc;
        a[mb][kf] = *(const half8*)((const char*)As + r * 128 + swz(r, kf * 64 + q * 16));
      }
#pragma unroll
    for (int nb = 0; nb < 8; ++nb)
#pragma unroll
      for (int kf = 0; kf < 2; ++kf) {
        const int r = wn * 128 + nb * 16 + lc;
        bb[nb][kf] = *(const half8*)((const char*)Bs + r * 128 + swz(r, kf * 64 + q * 16));
      }
#pragma unroll
    for (int kf = 0; kf < 2; ++kf)
#pragma unroll
      for (int mb = 0; mb < 2; ++mb)
#pragma unroll
        for (int nb = 0; nb < 8; ++nb)
          acc[mb][nb] = MFMA16(a[mb][kf], bb[nb][kf], acc[mb][nb]);
  }
#pragma unroll
  for (int mb = 0; mb < 2; ++mb)
#pragma unroll
    for (int nb = 0; nb < 8; ++nb)
#pragma unroll
      for (int j = 0; j < 4; ++j) {
        const int t = t0 + wt * 32 + mb * 16 + q * 4 + j;
        const int n = wn * 128 + nb * 16 + lc;
        q16[(size_t)t * 256 + n] = (f16)acc[mb][nb][j];
      }
}

// ---------------- K2: stage-once barrier-free QK + nt x-store + chunk stats ----
// grid 512: b = bid&7 (XCD pin), kc = bid>>3 (0..63, 64-s chunk). block 512 =
// 8 waves. Bs[64][256] staged once; ONE barrier; 8 t-passes (wave = 16 t each).
// Swapped-operand MFMA: lane holds x[s=q*4+j][t=lc] -> 4 nt f32x4 stores/pass.
__global__ __launch_bounds__(512, 2) void k_logits7(const float* __restrict__ mbank,
                                                    const f16* __restrict__ q16,
                                                    const int* __restrict__ mask,
                                                    float* __restrict__ alignv,
                                                    float* __restrict__ pstats) {
  __shared__ __align__(16) f16 Bs[64 * 256];  // [s][d] f16, 512B rows, swz (32 KB)
  const int tid = threadIdx.x;
  const int w = tid >> 6, l = tid & 63;
  const int q = l >> 4, lc = l & 15;
  const int bid = blockIdx.x;
  const int b = bid & 7;
  const int kc = bid >> 3;  // 0..63
  const int s0 = kc * 64;

  {  // stage Bs[64][256] fp32 -> f16, once
    const int r = tid >> 3;          // 0..63
    const int c0 = (tid & 7) * 32;   // f32 col base
    const float4* g = (const float4*)(mbank + ((size_t)b * NS + s0 + r) * ND + c0);
    float4 f[8];
#pragma unroll
    for (int i = 0; i < 8; ++i) f[i] = g[i];
#pragma unroll
    for (int i = 0; i < 4; ++i) {
      half8 h = {(f16)f[2 * i].x, (f16)f[2 * i].y, (f16)f[2 * i].z, (f16)f[2 * i].w,
                 (f16)f[2 * i + 1].x, (f16)f[2 * i + 1].y, (f16)f[2 * i + 1].z,
                 (f16)f[2 * i + 1].w};
      *(half8*)((char*)Bs + r * 512 + swz(r, c0 * 2 + i * 16)) = h;
    }
  }
  // hoist masks for this lane's s-positions (s = s0 + nb*16 + q*4 + j)
  int4 mk[4];
#pragma unroll
  for (int nb = 0; nb < 4; ++nb)
    mk[nb] = *(const int4*)(mask + (size_t)b * NS + s0 + nb * 16 + q * 4);
  __syncthreads();  // Bs read-only from here: no further barriers

  for (int p = 0; p < 8; ++p) {
    const int trow = p * 128 + w * 16 + lc;  // this lane's t
    // q fragments (B-operand role)
    half8 aq[8];
    {
      const f16* qrow = q16 + (size_t)(b * NT + trow) * 256;
#pragma unroll
      for (int kf = 0; kf < 8; ++kf)
        aq[kf] = *(const half8*)(qrow + kf * 32 + q * 8);
    }
    // xT[nb] = mb_frag * q_frag : lane holds s = q*4+j (row), t = lc (col)
    f32x4 xT[4];
#pragma unroll
    for (int i = 0; i < 4; ++i) xT[i] = (f32x4){0.f, 0.f, 0.f, 0.f};
#pragma unroll
    for (int kf = 0; kf < 8; ++kf)
#pragma unroll
      for (int nb = 0; nb < 4; ++nb) {
        const int rs = nb * 16 + lc;
        half8 mbf = *(const half8*)((const char*)Bs + rs * 512 + swz(rs, kf * 64 + q * 16));
        xT[nb] = MFMA16(mbf, aq[kf], xT[nb]);
      }
    // mask -> v -> nt f32x4 store + exact chunk stats
    float v[4][4];
    float vmax = NEGBIG;
    float* ab = alignv + ((size_t)b * NT + trow) * NS + s0;
#pragma unroll
    for (int nb = 0; nb < 4; ++nb) {
      v[nb][0] = mk[nb].x ? xT[nb][0] : NEGBIG;
      v[nb][1] = mk[nb].y ? xT[nb][1] : NEGBIG;
      v[nb][2] = mk[nb].z ? xT[nb][2] : NEGBIG;
      v[nb][3] = mk[nb].w ? xT[nb][3] : NEGBIG;
      f32x4 sv = {v[nb][0], v[nb][1], v[nb][2], v[nb][3]};
      __builtin_nontemporal_store(sv, (f32x4*)(ab + nb * 16 + q * 4));
      vmax = fmaxf(vmax, fmaxf(fmaxf(v[nb][0], v[nb][1]), fmaxf(v[nb][2], v[nb][3])));
    }
    vmax = fmaxf(vmax, __shfl_xor(vmax, 16));
    vmax = fmaxf(vmax, __shfl_xor(vmax, 32));
    float vsum = 0.f;
#pragma unroll
    for (int nb = 0; nb < 4; ++nb)
#pragma unroll
      for (int j = 0; j < 4; ++j) vsum += __expf(v[nb][j] - vmax);
    vsum += __shfl_xor(vsum, 16);
    vsum += __shfl_xor(vsum, 32);
    if (l < 16) {  // q==0 lanes hold one row each
      pstats[((size_t)(b * NT + trow) * 64 + kc) * 2 + 0] = vmax;
      pstats[((size_t)(b * NT + trow) * 64 + kc) * 2 + 1] = vsum;
    }
  }
}

// ---------------- K3: reduce 64 chunk partials -> m, 1/l per row ----------------
__global__ __launch_bounds__(256) void k_stats(const float* __restrict__ pstats,
                                               float* __restrict__ sm,
                                               float* __restrict__ slinv) {
  const int r = blockIdx.x * 256 + threadIdx.x;  // 0..8191
  const float4* p = (const float4*)(pstats + (size_t)r * 128);
  float mm = NEGBIG;
#pragma unroll
  for (int i = 0; i < 32; ++i) {
    float4 v = p[i];
    mm = fmaxf(mm, fmaxf(v.x, v.z));
  }
  float ll = 0.f;
#pragma unroll
  for (int i = 0; i < 32; ++i) {
    float4 v = p[i];
    ll += v.y * __expf(v.x - mm) + v.w * __expf(v.z - mm);
  }
  sm[r] = mm;
  slinv[r] = (ll > 0.f) ? (1.f / ll) : 0.f;
}

// ---------------- K4: p = exp(x-m)/l (in place) ; partial c = P@V ---- (frozen)
__global__ __launch_bounds__(512, 4) void k_pv(const float* __restrict__ mbank,
                                               const float* __restrict__ sm,
                                               const float* __restrict__ slinv,
                                               float* __restrict__ alignv,
                                               f16* __restrict__ pc) {
  __shared__ __align__(16) f16 VT[256 * 64];
  __shared__ __align__(16) f16 Ps[64 * 64];
  const int tid = threadIdx.x;
  const int w = tid >> 6, l = tid & 63;
  const int wtg = w >> 2, wd = w & 3;
  const int q = l >> 4, lc = l & 15;
  const int bid = blockIdx.x;
  const int b = bid & 7;
  const int kc = (bid >> 3) & 3;
  const int tt = bid >> 5;
  const int t0 = tt * 64;
  const int s0 = kc * 1024;

  const int pt = tid >> 3;
  const int ps8 = (tid & 7) * 8;
  const float mv = sm[(size_t)b * NT + t0 + pt];
  const float lv = slinv[(size_t)b * NT + t0 + pt];
  float* xrow = alignv + ((size_t)b * NT + t0 + pt) * NS + s0 + ps8;

  f32x4 acc[2][4];
#pragma unroll
  for (int i = 0; i < 2; ++i)
#pragma unroll
    for (int j = 0; j < 4; ++j) acc[i][j] = (f32x4){0.f, 0.f, 0.f, 0.f};

  const int dstage = (w & 3) * 64 + l;
  const int shalf = (w >> 2) * 32;

  float4 xA = ((const float4*)xrow)[0];
  float4 xB = ((const float4*)xrow)[1];

  for (int st = 0; st < 16; ++st) {
    const int sb = s0 + st * 64;
    __syncthreads();
    {
#pragma unroll
      for (int i = 0; i < 8; ++i) {
        const int s4 = shalf + i * 4;
        const float* g = mbank + ((size_t)b * NS + sb + s4) * ND + dstage;
        const float f0 = g[0], f1 = g[ND], f2 = g[2 * ND], f3 = g[3 * ND];
        half4v h = {(f16)f0, (f16)f1, (f16)f2, (f16)f3};
        *(half4v*)((char*)VT + dstage * 128 + swz(dstage, s4 * 2)) = h;
      }
    }
    {
      const float p0 = __expf(xA.x - mv) * lv, p1 = __expf(xA.y - mv) * lv;
      const float p2 = __expf(xA.z - mv) * lv, p3 = __expf(xA.w - mv) * lv;
      const float p4 = __expf(xB.x - mv) * lv, p5 = __expf(xB.y - mv) * lv;
      const float p6 = __expf(xB.z - mv) * lv, p7 = __expf(xB.w - mv) * lv;
      float* xp = xrow + st * 64;
      ((float4*)xp)[0] = (float4){p0, p1, p2, p3};
      ((float4*)xp)[1] = (float4){p4, p5, p6, p7};
      half8 h = {(f16)p0, (f16)p1, (f16)p2, (f16)p3,
                 (f16)p4, (f16)p5, (f16)p6, (f16)p7};
      *(half8*)((char*)Ps + pt * 128 + swz(pt, ps8 * 2)) = h;
    }
    if (st < 15) {
      const float* xn = xrow + (st + 1) * 64;
      xA = ((const float4*)xn)[0];
      xB = ((const float4*)xn)[1];
    }
    __syncthreads();
    half8 a[2][2];
#pragma unroll
    for (int mb = 0; mb < 2; ++mb)
#pragma unroll
      for (int kf = 0; kf < 2; ++kf) {
        const int r = wtg * 32 + mb * 16 + lc;
        a[mb][kf] = *(const half8*)((const char*)Ps + r * 128 + swz(r, kf * 64 + q * 16));
      }
#pragma unroll
    for (int kf = 0; kf < 2; ++kf)
#pragma unroll
      for (int nb = 0; nb < 4; ++nb) {
        const int d = wd * 64 + nb * 16 + lc;
        half8 bbt = *(const half8*)((const char*)VT + d * 128 + swz(d, kf * 64 + q * 16));
#pragma unroll
        for (int mb = 0; mb < 2; ++mb)
          acc[mb][nb] = MFMA16(a[mb][kf], bbt, acc[mb][nb]);
      }
  }

#pragma unroll
  for (int mb = 0; mb < 2; ++mb)
#pragma unroll
    for (int nb = 0; nb < 4; ++nb)
#pragma unroll
      for (int j = 0; j < 4; ++j) {
        const int t = t0 + wtg * 32 + mb * 16 + q * 4 + j;
        const int d = wd * 64 + nb * 16 + lc;
        pc[(size_t)kc * ((size_t)NBATCH * NT * ND) + ((size_t)b * NT + t) * ND + d] =
            (f16)acc[mb][nb][j];
      }
}

// ---------------- K5: c = sum of 4 fp16 split-K partials ---------------- (frozen)
__global__ __launch_bounds__(256) void k_csum(const f16* __restrict__ pc,
                                              float* __restrict__ outc) {
  const size_t i8 = ((size_t)blockIdx.x * 256 + threadIdx.x) * 8;
  const size_t STRIDE = (size_t)NBATCH * NT * ND;
  half8 a = *(const half8*)(pc + i8);
  half8 b = *(const half8*)(pc + STRIDE + i8);
  half8 c = *(const half8*)(pc + 2 * STRIDE + i8);
  half8 d = *(const half8*)(pc + 3 * STRIDE + i8);
  float4 r0, r1;
  r0.x = (float)a[0] + (float)b[0] + (float)c[0] + (float)d[0];
  r0.y = (float)a[1] + (float)b[1] + (float)c[1] + (float)d[1];
  r0.z = (float)a[2] + (float)b[2] + (float)c[2] + (float)d[2];
  r0.w = (float)a[3] + (float)b[3] + (float)c[3] + (float)d[3];
  r1.x = (float)a[4] + (float)b[4] + (float)c[4] + (float)d[4];
  r1.y = (float)a[5] + (float)b[5] + (float)c[5] + (float)d[5];
  r1.z = (float)a[6] + (float)b[6] + (float)c[6] + (float)d[6];
  r1.w = (float)a[7] + (float)b[7] + (float)c[7] + (float)d[7];
  *(float4*)(outc + i8) = r0;
  *(float4*)(outc + i8 + 4) = r1;
}

extern "C" void kernel_launch(void* const* d_in, const int* in_sizes, int n_in,
                              void* d_out, int out_size, void* d_ws, size_t ws_size,
                              hipStream_t stream) {
  const float* mbank = (const float*)d_in[0];  // (8,4096,256) f32
  const float* src   = (const float*)d_in[1];  // (8,1024,256) f32
  const int*   mask  = (const int*)d_in[2];    // (8,4096) bool->int
  const float* W     = (const float*)d_in[3];  // (256,256) f32

  float* out_c = (float*)d_out;
  float* out_align = out_c + (size_t)NBATCH * NT * ND;

  // ws layout (24.1 MB total; proven budget >= 33.6 MB from R2):
  //   [0, 4 MB)          q16   : 8192x256 fp16
  //   [4 MB, 8 MB)       pstats: 8192x64x2 f32
  //   [8 MB, 24 MB)      pc    : 4 x 2M fp16 split-K partials
  //   [24 MB, +32 KB)    sm
  //   [24 MB+32K, +32K)  slinv
  char* ws = (char*)d_ws;
  f16* q16      = (f16*)ws;
  float* pstats = (float*)(ws + (4 << 20));
  f16* pc       = (f16*)(ws + (8 << 20));
  float* sm     = (float*)(ws + (24 << 20));
  float* slinv  = (float*)(ws + (24 << 20) + (32 << 10));

  hipLaunchKernelGGL(k_qproj, dim3(128), dim3(256), 0, stream, src, W, q16);
  hipLaunchKernelGGL(k_logits7, dim3(512), dim3(512), 0, stream,
                     mbank, q16, mask, out_align, pstats);
  hipLaunchKernelGGL(k_stats, dim3(32), dim3(256), 0, stream, pstats, sm, slinv);
  hipLaunchKernelGGL(k_pv, dim3(512), dim3(512), 0, stream,
                     mbank, sm, slinv, out_align, pc);
  hipLaunchKernelGGL(k_csum, dim3(1024), dim3(256), 0, stream, pc, out_c);
}

// Round 14
// 159.551 us; speedup vs baseline: 1.1212x; 1.0689x over previous
//
#include <hip/hip_runtime.h>
#include <cstdint>
#include <cstddef>

// GlobalAttention (Luong 'general'): q = src@W^T ; x = q@MB^T ; softmax(mask) ; c = P@MB
// Outputs: d_out = [ c (8*1024*256) | align_vectors (8*1024*4096) ] fp32.
// Pipeline: k_qproj -> k_logits7 (stage-once, barrier-free, nt x-store, exact
//   64-chunk stats) -> k_stats -> k_pv (2-deep nt x-prefetch + PV) -> k_csum
//
// R14: R13 showed logits7 is fast (left top-5) but nt-stored x made k_pv's
// x-reads HBM-sourced (FETCH 31->95 MB) and its 1-step prefetch (sized for
// ~200cy L2) exposed ~900cy HBM latency -> pv 38->102 us. Fix pv only:
// (1) 2-step double-buffered x prefetch (loads issued during prior PV phase,
// >1500cy cover), (2) nontemporal x loads (read-once; protect mbank L2 set).

typedef _Float16 f16;
typedef _Float16 half8 __attribute__((ext_vector_type(8)));
typedef _Float16 half4v __attribute__((ext_vector_type(4)));
typedef float f32x4 __attribute__((ext_vector_type(4)));

#define MFMA16(a, b, c) __builtin_amdgcn_mfma_f32_16x16x32_f16((a), (b), (c), 0, 0, 0)

static constexpr int NBATCH = 8;
static constexpr int NT = 1024;   // TGT
static constexpr int NS = 4096;   // SRC
static constexpr int ND = 256;    // SDIM == TDIM
static constexpr float NEGBIG = -3.0e38f;

__device__ __forceinline__ int swz(int row, int byteInRow) {
  return byteInRow ^ ((row & 7) << 4);
}

// ---------------- K1: q16 = source @ W^T (fp16 out) ---------------- (frozen)
__global__ __launch_bounds__(256) void k_qproj(const float* __restrict__ src,
                                               const float* __restrict__ W,
                                               f16* __restrict__ q16) {
  __shared__ __align__(16) f16 As[64 * 64];
  __shared__ __align__(16) f16 Bs[256 * 64];
  const int tid = threadIdx.x;
  const int w = tid >> 6, l = tid & 63;
  const int wt = w >> 1, wn = w & 1;
  const int q = l >> 4, lc = l & 15;
  const int t0 = blockIdx.x * 64;

  f32x4 acc[2][8];
#pragma unroll
  for (int i = 0; i < 2; ++i)
#pragma unroll
    for (int j = 0; j < 8; ++j) acc[i][j] = (f32x4){0.f, 0.f, 0.f, 0.f};

  for (int k0 = 0; k0 < 256; k0 += 64) {
    __syncthreads();
    {
      const int r = tid >> 2, c2 = (tid & 3) * 2;
      const float* g = src + (size_t)(t0 + r) * 256 + k0 + c2 * 8;
      float4 f0 = ((const float4*)g)[0], f1 = ((const float4*)g)[1];
      float4 f2 = ((const float4*)g)[2], f3 = ((const float4*)g)[3];
      half8 h0 = {(f16)f0.x, (f16)f0.y, (f16)f0.z, (f16)f0.w,
                  (f16)f1.x, (f16)f1.y, (f16)f1.z, (f16)f1.w};
      half8 h1 = {(f16)f2.x, (f16)f2.y, (f16)f2.z, (f16)f2.w,
                  (f16)f3.x, (f16)f3.y, (f16)f3.z, (f16)f3.w};
      *(half8*)((char*)As + r * 128 + swz(r, c2 * 16)) = h0;
      *(half8*)((char*)As + r * 128 + swz(r, c2 * 16 + 16)) = h1;
    }
    {
      const int n = tid;
      const float* g = W + (size_t)n * 256 + k0;
#pragma unroll
      for (int c = 0; c < 8; ++c) {
        float4 f0 = ((const float4*)(g + c * 8))[0];
        float4 f1 = ((const float4*)(g + c * 8))[1];
        half8 h = {(f16)f0.x, (f16)f0.y, (f16)f0.z, (f16)f0.w,
                   (f16)f1.x, (f16)f1.y, (f16)f1.z, (f16)f1.w};
        *(half8*)((char*)Bs + n * 128 + swz(n, c * 16)) = h;
      }
    }
    __syncthreads();
    half8 a[2][2], bb[8][2];
#pragma unroll
    for (int mb = 0; mb < 2; ++mb)
#pragma unroll
      for (int kf = 0; kf < 2; ++kf) {
        const int r = wt * 32 + mb * 16 + lc;
        a[mb][kf] = *(const half8*)((const char*)As + r * 128 + swz(r, kf * 64 + q * 16));
      }
#pragma unroll
    for (int nb = 0; nb < 8; ++nb)
#pragma unroll
      for (int kf = 0; kf < 2; ++kf) {
        const int r = wn * 128 + nb * 16 + lc;
        bb[nb][kf] = *(const half8*)((const char*)Bs + r * 128 + swz(r, kf * 64 + q * 16));
      }
#pragma unroll
    for (int kf = 0; kf < 2; ++kf)
#pragma unroll
      for (int mb = 0; mb < 2; ++mb)
#pragma unroll
        for (int nb = 0; nb < 8; ++nb)
          acc[mb][nb] = MFMA16(a[mb][kf], bb[nb][kf], acc[mb][nb]);
  }
#pragma unroll
  for (int mb = 0; mb < 2; ++mb)
#pragma unroll
    for (int nb = 0; nb < 8; ++nb)
#pragma unroll
      for (int j = 0; j < 4; ++j) {
        const int t = t0 + wt * 32 + mb * 16 + q * 4 + j;
        const int n = wn * 128 + nb * 16 + lc;
        q16[(size_t)t * 256 + n] = (f16)acc[mb][nb][j];
      }
}

// ---------------- K2: stage-once barrier-free QK + nt x-store ---- (frozen R13)
__global__ __launch_bounds__(512, 2) void k_logits7(const float* __restrict__ mbank,
                                                    const f16* __restrict__ q16,
                                                    const int* __restrict__ mask,
                                                    float* __restrict__ alignv,
                                                    float* __restrict__ pstats) {
  __shared__ __align__(16) f16 Bs[64 * 256];  // [s][d] f16, 512B rows, swz (32 KB)
  const int tid = threadIdx.x;
  const int w = tid >> 6, l = tid & 63;
  const int q = l >> 4, lc = l & 15;
  const int bid = blockIdx.x;
  const int b = bid & 7;
  const int kc = bid >> 3;  // 0..63
  const int s0 = kc * 64;

  {  // stage Bs[64][256] fp32 -> f16, once
    const int r = tid >> 3;
    const int c0 = (tid & 7) * 32;
    const float4* g = (const float4*)(mbank + ((size_t)b * NS + s0 + r) * ND + c0);
    float4 f[8];
#pragma unroll
    for (int i = 0; i < 8; ++i) f[i] = g[i];
#pragma unroll
    for (int i = 0; i < 4; ++i) {
      half8 h = {(f16)f[2 * i].x, (f16)f[2 * i].y, (f16)f[2 * i].z, (f16)f[2 * i].w,
                 (f16)f[2 * i + 1].x, (f16)f[2 * i + 1].y, (f16)f[2 * i + 1].z,
                 (f16)f[2 * i + 1].w};
      *(half8*)((char*)Bs + r * 512 + swz(r, c0 * 2 + i * 16)) = h;
    }
  }
  int4 mk[4];
#pragma unroll
  for (int nb = 0; nb < 4; ++nb)
    mk[nb] = *(const int4*)(mask + (size_t)b * NS + s0 + nb * 16 + q * 4);
  __syncthreads();  // Bs read-only from here: no further barriers

  for (int p = 0; p < 8; ++p) {
    const int trow = p * 128 + w * 16 + lc;
    half8 aq[8];
    {
      const f16* qrow = q16 + (size_t)(b * NT + trow) * 256;
#pragma unroll
      for (int kf = 0; kf < 8; ++kf)
        aq[kf] = *(const half8*)(qrow + kf * 32 + q * 8);
    }
    f32x4 xT[4];
#pragma unroll
    for (int i = 0; i < 4; ++i) xT[i] = (f32x4){0.f, 0.f, 0.f, 0.f};
#pragma unroll
    for (int kf = 0; kf < 8; ++kf)
#pragma unroll
      for (int nb = 0; nb < 4; ++nb) {
        const int rs = nb * 16 + lc;
        half8 mbf = *(const half8*)((const char*)Bs + rs * 512 + swz(rs, kf * 64 + q * 16));
        xT[nb] = MFMA16(mbf, aq[kf], xT[nb]);
      }
    float v[4][4];
    float vmax = NEGBIG;
    float* ab = alignv + ((size_t)b * NT + trow) * NS + s0;
#pragma unroll
    for (int nb = 0; nb < 4; ++nb) {
      v[nb][0] = mk[nb].x ? xT[nb][0] : NEGBIG;
      v[nb][1] = mk[nb].y ? xT[nb][1] : NEGBIG;
      v[nb][2] = mk[nb].z ? xT[nb][2] : NEGBIG;
      v[nb][3] = mk[nb].w ? xT[nb][3] : NEGBIG;
      f32x4 sv = {v[nb][0], v[nb][1], v[nb][2], v[nb][3]};
      __builtin_nontemporal_store(sv, (f32x4*)(ab + nb * 16 + q * 4));
      vmax = fmaxf(vmax, fmaxf(fmaxf(v[nb][0], v[nb][1]), fmaxf(v[nb][2], v[nb][3])));
    }
    vmax = fmaxf(vmax, __shfl_xor(vmax, 16));
    vmax = fmaxf(vmax, __shfl_xor(vmax, 32));
    float vsum = 0.f;
#pragma unroll
    for (int nb = 0; nb < 4; ++nb)
#pragma unroll
      for (int j = 0; j < 4; ++j) vsum += __expf(v[nb][j] - vmax);
    vsum += __shfl_xor(vsum, 16);
    vsum += __shfl_xor(vsum, 32);
    if (l < 16) {
      pstats[((size_t)(b * NT + trow) * 64 + kc) * 2 + 0] = vmax;
      pstats[((size_t)(b * NT + trow) * 64 + kc) * 2 + 1] = vsum;
    }
  }
}

// ---------------- K3: reduce 64 chunk partials -> m, 1/l per row ----------------
__global__ __launch_bounds__(256) void k_stats(const float* __restrict__ pstats,
                                               float* __restrict__ sm,
                                               float* __restrict__ slinv) {
  const int r = blockIdx.x * 256 + threadIdx.x;
  const float4* p = (const float4*)(pstats + (size_t)r * 128);
  float mm = NEGBIG;
#pragma unroll
  for (int i = 0; i < 32; ++i) {
    float4 v = p[i];
    mm = fmaxf(mm, fmaxf(v.x, v.z));
  }
  float ll = 0.f;
#pragma unroll
  for (int i = 0; i < 32; ++i) {
    float4 v = p[i];
    ll += v.y * __expf(v.x - mm) + v.w * __expf(v.z - mm);
  }
  sm[r] = mm;
  slinv[r] = (ll > 0.f) ? (1.f / ll) : 0.f;
}

// ---------------- K4: p = exp(x-m)/l ; partial c = P@V ----
// R14: 2-step double-buffered NONTEMPORAL x prefetch (x now HBM-sourced since
// logits7 nt-stores it). Loads for step st+2 issue during step st's PV phase.
__global__ __launch_bounds__(512, 4) void k_pv(const float* __restrict__ mbank,
                                               const float* __restrict__ sm,
                                               const float* __restrict__ slinv,
                                               float* __restrict__ alignv,
                                               f16* __restrict__ pc) {
  __shared__ __align__(16) f16 VT[256 * 64];
  __shared__ __align__(16) f16 Ps[64 * 64];
  const int tid = threadIdx.x;
  const int w = tid >> 6, l = tid & 63;
  const int wtg = w >> 2, wd = w & 3;
  const int q = l >> 4, lc = l & 15;
  const int bid = blockIdx.x;
  const int b = bid & 7;
  const int kc = (bid >> 3) & 3;
  const int tt = bid >> 5;
  const int t0 = tt * 64;
  const int s0 = kc * 1024;

  const int pt = tid >> 3;
  const int ps8 = (tid & 7) * 8;
  const float mv = sm[(size_t)b * NT + t0 + pt];
  const float lv = slinv[(size_t)b * NT + t0 + pt];
  float* xrow = alignv + ((size_t)b * NT + t0 + pt) * NS + s0 + ps8;

  f32x4 acc[2][4];
#pragma unroll
  for (int i = 0; i < 2; ++i)
#pragma unroll
    for (int j = 0; j < 4; ++j) acc[i][j] = (f32x4){0.f, 0.f, 0.f, 0.f};

  const int dstage = (w & 3) * 64 + l;
  const int shalf = (w >> 2) * 32;

  // 2-deep nontemporal x prefetch: slot st&1 holds step st's data
  f32x4 xbufA[2], xbufB[2];
  xbufA[0] = __builtin_nontemporal_load((const f32x4*)(xrow));
  xbufB[0] = __builtin_nontemporal_load((const f32x4*)(xrow + 4));
  xbufA[1] = __builtin_nontemporal_load((const f32x4*)(xrow + 64));
  xbufB[1] = __builtin_nontemporal_load((const f32x4*)(xrow + 68));

  for (int st = 0; st < 16; ++st) {
    const int sb = s0 + st * 64;
    const int cur = st & 1;
    __syncthreads();
    {
#pragma unroll
      for (int i = 0; i < 8; ++i) {
        const int s4 = shalf + i * 4;
        const float* g = mbank + ((size_t)b * NS + sb + s4) * ND + dstage;
        const float f0 = g[0], f1 = g[ND], f2 = g[2 * ND], f3 = g[3 * ND];
        half4v h = {(f16)f0, (f16)f1, (f16)f2, (f16)f3};
        *(half4v*)((char*)VT + dstage * 128 + swz(dstage, s4 * 2)) = h;
      }
    }
    {
      const f32x4 xA = xbufA[cur], xB = xbufB[cur];
      const float p0 = __expf(xA[0] - mv) * lv, p1 = __expf(xA[1] - mv) * lv;
      const float p2 = __expf(xA[2] - mv) * lv, p3 = __expf(xA[3] - mv) * lv;
      const float p4 = __expf(xB[0] - mv) * lv, p5 = __expf(xB[1] - mv) * lv;
      const float p6 = __expf(xB[2] - mv) * lv, p7 = __expf(xB[3] - mv) * lv;
      float* xp = xrow + st * 64;
      ((float4*)xp)[0] = (float4){p0, p1, p2, p3};
      ((float4*)xp)[1] = (float4){p4, p5, p6, p7};
      half8 h = {(f16)p0, (f16)p1, (f16)p2, (f16)p3,
                 (f16)p4, (f16)p5, (f16)p6, (f16)p7};
      *(half8*)((char*)Ps + pt * 128 + swz(pt, ps8 * 2)) = h;
    }
    if (st + 2 < 16) {  // prefetch step st+2 into the slot just freed
      const float* xn = xrow + (st + 2) * 64;
      xbufA[cur] = __builtin_nontemporal_load((const f32x4*)(xn));
      xbufB[cur] = __builtin_nontemporal_load((const f32x4*)(xn + 4));
    }
    __syncthreads();
    half8 a[2][2];
#pragma unroll
    for (int mb = 0; mb < 2; ++mb)
#pragma unroll
      for (int kf = 0; kf < 2; ++kf) {
        const int r = wtg * 32 + mb * 16 + lc;
        a[mb][kf] = *(const half8*)((const char*)Ps + r * 128 + swz(r, kf * 64 + q * 16));
      }
#pragma unroll
    for (int kf = 0; kf < 2; ++kf)
#pragma unroll
      for (int nb = 0; nb < 4; ++nb) {
        const int d = wd * 64 + nb * 16 + lc;
        half8 bbt = *(const half8*)((const char*)VT + d * 128 + swz(d, kf * 64 + q * 16));
#pragma unroll
        for (int mb = 0; mb < 2; ++mb)
          acc[mb][nb] = MFMA16(a[mb][kf], bbt, acc[mb][nb]);
      }
  }

#pragma unroll
  for (int mb = 0; mb < 2; ++mb)
#pragma unroll
    for (int nb = 0; nb < 4; ++nb)
#pragma unroll
      for (int j = 0; j < 4; ++j) {
        const int t = t0 + wtg * 32 + mb * 16 + q * 4 + j;
        const int d = wd * 64 + nb * 16 + lc;
        pc[(size_t)kc * ((size_t)NBATCH * NT * ND) + ((size_t)b * NT + t) * ND + d] =
            (f16)acc[mb][nb][j];
      }
}

// ---------------- K5: c = sum of 4 fp16 split-K partials ---------------- (frozen)
__global__ __launch_bounds__(256) void k_csum(const f16* __restrict__ pc,
                                              float* __restrict__ outc) {
  const size_t i8 = ((size_t)blockIdx.x * 256 + threadIdx.x) * 8;
  const size_t STRIDE = (size_t)NBATCH * NT * ND;
  half8 a = *(const half8*)(pc + i8);
  half8 b = *(const half8*)(pc + STRIDE + i8);
  half8 c = *(const half8*)(pc + 2 * STRIDE + i8);
  half8 d = *(const half8*)(pc + 3 * STRIDE + i8);
  float4 r0, r1;
  r0.x = (float)a[0] + (float)b[0] + (float)c[0] + (float)d[0];
  r0.y = (float)a[1] + (float)b[1] + (float)c[1] + (float)d[1];
  r0.z = (float)a[2] + (float)b[2] + (float)c[2] + (float)d[2];
  r0.w = (float)a[3] + (float)b[3] + (float)c[3] + (float)d[3];
  r1.x = (float)a[4] + (float)b[4] + (float)c[4] + (float)d[4];
  r1.y = (float)a[5] + (float)b[5] + (float)c[5] + (float)d[5];
  r1.z = (float)a[6] + (float)b[6] + (float)c[6] + (float)d[6];
  r1.w = (float)a[7] + (float)b[7] + (float)c[7] + (float)d[7];
  *(float4*)(outc + i8) = r0;
  *(float4*)(outc + i8 + 4) = r1;
}

extern "C" void kernel_launch(void* const* d_in, const int* in_sizes, int n_in,
                              void* d_out, int out_size, void* d_ws, size_t ws_size,
                              hipStream_t stream) {
  const float* mbank = (const float*)d_in[0];  // (8,4096,256) f32
  const float* src   = (const float*)d_in[1];  // (8,1024,256) f32
  const int*   mask  = (const int*)d_in[2];    // (8,4096) bool->int
  const float* W     = (const float*)d_in[3];  // (256,256) f32

  float* out_c = (float*)d_out;
  float* out_align = out_c + (size_t)NBATCH * NT * ND;

  // ws layout (24.1 MB used; proven budget >= 33.6 MB from R2):
  //   [0, 4 MB)          q16   : 8192x256 fp16
  //   [4 MB, 8 MB)       pstats: 8192x64x2 f32
  //   [8 MB, 24 MB)      pc    : 4 x 2M fp16 split-K partials
  //   [24 MB, +32 KB)    sm
  //   [24 MB+32K, +32K)  slinv
  char* ws = (char*)d_ws;
  f16* q16      = (f16*)ws;
  float* pstats = (float*)(ws + (4 << 20));
  f16* pc       = (f16*)(ws + (8 << 20));
  float* sm     = (float*)(ws + (24 << 20));
  float* slinv  = (float*)(ws + (24 << 20) + (32 << 10));

  hipLaunchKernelGGL(k_qproj, dim3(128), dim3(256), 0, stream, src, W, q16);
  hipLaunchKernelGGL(k_logits7, dim3(512), dim3(512), 0, stream,
                     mbank, q16, mask, out_align, pstats);
  hipLaunchKernelGGL(k_stats, dim3(32), dim3(256), 0, stream, pstats, sm, slinv);
  hipLaunchKernelGGL(k_pv, dim3(512), dim3(512), 0, stream,
                     mbank, sm, slinv, out_align, pc);
  hipLaunchKernelGGL(k_csum, dim3(1024), dim3(256), 0, stream, pc, out_c);
}